// Round 19
// baseline (277.801 us; speedup 1.0000x reference)
//
#include <hip/hip_runtime.h>
#include <hip/hip_bf16.h>
#include <math.h>

typedef short short8 __attribute__((ext_vector_type(8)));
typedef float f32x4  __attribute__((ext_vector_type(4)));
typedef float f32x2  __attribute__((ext_vector_type(2)));
typedef unsigned int u32;

#define B_ROWS 8192
#define IN_DIM 1024
#define OUT_DIM 256
#define M_DIM 1280
#define P_DIM 2304
#define NJ 10
#define RB 32                  // rows per block -> 256 blocks, 1 block/CU
#define HG_COLS 1152

// ws: Xbf bf16[8192][1024] ; Wbf bf16[1280][2304] ; Hg bf16[8192][1152]
#define WBF_OFF (B_ROWS * (size_t)IN_DIM * 2)
#define HG_OFF  (WBF_OFF + (size_t)M_DIM * P_DIM * 2)

__device__ __forceinline__ short f2bf(float x)
{
    __hip_bfloat16 h = __float2bfloat16(x);
    return *(short*)&h;
}

__device__ __forceinline__ float tanh_fast(float x)
{
    float e = __expf(2.f * x);
    return 1.f - 2.f * __builtin_amdgcn_rcpf(e + 1.f);
}

__device__ __forceinline__ float sigmoid_fast(float y)
{
    return __builtin_amdgcn_rcpf(1.f + __expf(-y));
}

__device__ __forceinline__ void pk_fma_bcast(f32x2& d, f32x2 w, f32x2 h)
{
    asm("v_pk_fma_f32 %0, %1, %2, %0 op_sel_hi:[1,0,1]"
        : "+v"(d) : "v"(w), "v"(h));
}

__global__ __launch_bounds__(256)
void convert_x(const float* __restrict__ x, short* __restrict__ Xbf)
{
    int idx = blockIdx.x * 256 + threadIdx.x;
    int r  = idx >> 7;
    int c8 = (idx & 127) << 3;
    const float* src = x + (size_t)r * IN_DIM + c8;
    float4 a0 = *(const float4*)src;
    float4 a1 = *(const float4*)(src + 4);
    short8 s;
    s[0] = f2bf(a0.x); s[1] = f2bf(a0.y); s[2] = f2bf(a0.z); s[3] = f2bf(a0.w);
    s[4] = f2bf(a1.x); s[5] = f2bf(a1.y); s[6] = f2bf(a1.z); s[7] = f2bf(a1.w);
    *(short8*)(Xbf + (size_t)r * IN_DIM + c8) = s;
}

__global__ __launch_bounds__(256)
void convert_w(const float* __restrict__ W, short* __restrict__ Wbf)
{
    size_t e8 = ((size_t)blockIdx.x * 256 + threadIdx.x) * 8;
    float4 a0 = *(const float4*)(W + e8);
    float4 a1 = *(const float4*)(W + e8 + 4);
    short8 s;
    s[0] = f2bf(a0.x); s[1] = f2bf(a0.y); s[2] = f2bf(a0.z); s[3] = f2bf(a0.w);
    s[4] = f2bf(a1.x); s[5] = f2bf(a1.y); s[6] = f2bf(a1.z); s[7] = f2bf(a1.w);
    *(short8*)(Wbf + e8) = s;
}

// LDS (97,280 B, no union hazards across concurrent phases):
//  PreL f32[32][132] @0 (16,896) ; lwf f32[128][140] @16896 (71,680, ends 88,576)
//  hbuf bf16[32][136] @88576 (8,704, ends 97,280)
#define PRL_OFF 0
#define LWF_OFF 16896
#define HBF_OFF 88576
#define PLS 132
#define LWS 140
#define HBS 136

__global__ __launch_bounds__(512, 1)
void fused(const short* __restrict__ Xbf, const short* __restrict__ Wbf,
           const float* __restrict__ Wf, short* __restrict__ Hg,
           const float* __restrict__ bias, float* __restrict__ out)
{
    __shared__ __align__(16) char L[97280];
    float* PreL = (float*)(L + PRL_OFF);
    float* lwf  = (float*)(L + LWF_OFF);
    short* hbuf = (short*)(L + HBF_OFF);

    const int tid  = threadIdx.x;
    const int lane = tid & 63;
    const int w    = tid >> 6;        // wave 0..7
    const bool gw  = (w < 4);         // gemm waves 0..3, seq waves 4..7
    const int bm   = blockIdx.x * RB;

    // ---- gemm-wave indices ----
    const int ar  = lane & 15;        // fragment row index
    const int fq  = lane >> 4;        // k-quarter / output row-quad
    const int kc8 = fq * 8;           // k offset (shorts)
    const int cn0 = (w & 3) * 32 + ar;
    const int cn1 = cn0 + 16;

    // ---- seq-wave indices ----
    const int r8   = lane & 7;        // row within wave's 8
    const int slq  = lane >> 3;       // slice 0..7 (16 u's each)
    const int srow = (w - 4) * 8 + r8;            // 0..31 (seq waves only)
    const int colb = slq * 16 + ((slq >> 1) << 2); // swizzled lwf col base
    const int lt   = tid & 255;       // seq-local tid for staging

    // A-fragment loader (rows of Xbf / Hg panel)
    auto ldA = [&](int ri, int k) -> short8 {
        const short* p = (k < IN_DIM)
            ? (Xbf + (size_t)(bm + ri * 16 + ar) * IN_DIM + k + kc8)
            : (Hg  + (size_t)(bm + ri * 16 + ar) * HG_COLS + (k - IN_DIM) + kc8);
        return *(const short8*)p;
    };
    auto ldB = [&](int j0p, int ci, int k) -> short8 {
        return *(const short8*)(Wbf + (size_t)(j0p + (w & 3) * 32 + ci * 16 + ar) * P_DIM + k + kc8);
    };

    f32x4 acc00, acc01, acc10, acc11;
    auto zacc = [&]() {
        acc00 = (f32x4){0.f,0.f,0.f,0.f}; acc01 = acc00;
        acc10 = acc00; acc11 = acc00;
    };
    struct KSet { short8 a0k0, a1k0, b0k0, b1k0, a0k1, a1k1, b0k1, b1k1; };
    auto issueT = [&](KSet& S, int j0p, int k0) {
        S.a0k0 = ldA(0, k0);       S.a1k0 = ldA(1, k0);
        S.b0k0 = ldB(j0p, 0, k0);  S.b1k0 = ldB(j0p, 1, k0);
        S.a0k1 = ldA(0, k0 + 32);      S.a1k1 = ldA(1, k0 + 32);
        S.b0k1 = ldB(j0p, 0, k0 + 32); S.b1k1 = ldB(j0p, 1, k0 + 32);
    };
    auto mfmaT = [&](KSet& S) {
        acc00 = __builtin_amdgcn_mfma_f32_16x16x32_bf16(S.a0k0, S.b0k0, acc00, 0, 0, 0);
        acc01 = __builtin_amdgcn_mfma_f32_16x16x32_bf16(S.a0k0, S.b1k0, acc01, 0, 0, 0);
        acc10 = __builtin_amdgcn_mfma_f32_16x16x32_bf16(S.a1k0, S.b0k0, acc10, 0, 0, 0);
        acc11 = __builtin_amdgcn_mfma_f32_16x16x32_bf16(S.a1k0, S.b1k0, acc11, 0, 0, 0);
        acc00 = __builtin_amdgcn_mfma_f32_16x16x32_bf16(S.a0k1, S.b0k1, acc00, 0, 0, 0);
        acc01 = __builtin_amdgcn_mfma_f32_16x16x32_bf16(S.a0k1, S.b1k1, acc01, 0, 0, 0);
        acc10 = __builtin_amdgcn_mfma_f32_16x16x32_bf16(S.a1k1, S.b0k1, acc10, 0, 0, 0);
        acc11 = __builtin_amdgcn_mfma_f32_16x16x32_bf16(S.a1k1, S.b1k1, acc11, 0, 0, 0);
    };
    auto run_main = [&](int j0p, int Km) {
        zacc();
        KSet S0, S1;
        issueT(S0, j0p, 0);
        issueT(S1, j0p, 64);
#pragma unroll 1
        for (int k0 = 0; k0 < Km; k0 += 128) {
            mfmaT(S0);
            if (k0 + 128 < Km) issueT(S0, j0p, k0 + 128);
            mfmaT(S1);
            if (k0 + 192 < Km) issueT(S1, j0p, k0 + 192);
        }
    };
    auto write_prel = [&](int j0p) {
        float bv0 = bias[j0p + cn0];
        float bv1 = bias[j0p + cn1];
#pragma unroll
        for (int r = 0; r < 4; ++r) {
            PreL[(fq * 4 + r) * PLS + cn0]        = acc00[r] + bv0;
            PreL[(fq * 4 + r) * PLS + cn1]        = acc01[r] + bv1;
            PreL[(16 + fq * 4 + r) * PLS + cn0]   = acc10[r] + bv0;
            PreL[(16 + fq * 4 + r) * PLS + cn1]   = acc11[r] + bv1;
        }
    };
    auto stage_lwf = [&](int j0n) {     // seq waves: lwf for block j0n (tri-zeroed)
        int u = lt & 127, th = lt >> 7;
        int cu = u + ((u >> 5) << 2);
#pragma unroll
        for (int it = 0; it < 16; ++it) {
            int t4 = (it * 2 + th) * 4;
            float4 v = *(const float4*)(Wf + (size_t)(j0n + u) * P_DIM + IN_DIM + j0n + t4);
            lwf[(t4 + 0) * LWS + cu] = (u > t4 + 0) ? v.x : 0.f;
            lwf[(t4 + 1) * LWS + cu] = (u > t4 + 1) ? v.y : 0.f;
            lwf[(t4 + 2) * LWS + cu] = (u > t4 + 2) ? v.z : 0.f;
            lwf[(t4 + 3) * LWS + cu] = (u > t4 + 3) ? v.w : 0.f;
        }
    };

    // ================= prologue: PreL(J=0) by gemm waves; lwf(0) by seq =====
    if (gw) {
        run_main(0, IN_DIM);
        write_prel(0);
    } else {
        stage_lwf(0);
    }
    __syncthreads();

#pragma unroll 1
    for (int J = 0; J < NJ; ++J) {
        const int j0 = J * 128;

        // =========== overlap phase ===========
        if (gw) {
            if (J < 9) run_main(j0 + 128, IN_DIM + j0);   // main-K for J+1
        } else {
            // ---- seq J: load PreL, run 128 steps, write h ----
            f32x2 p0, p1, p2, p3, p4, p5, p6, p7;
            {
                const float* pr = PreL + srow * PLS + slq * 16;
                p0 = *(const f32x2*)pr;       p1 = *(const f32x2*)(pr + 2);
                p2 = *(const f32x2*)(pr + 4); p3 = *(const f32x2*)(pr + 6);
                p4 = *(const f32x2*)(pr + 8); p5 = *(const f32x2*)(pr + 10);
                p6 = *(const f32x2*)(pr + 12); p7 = *(const f32x2*)(pr + 14);
            }
            const float* lwb = lwf + colb;
#pragma unroll 1
            for (int g = 0; g < 8; ++g) {
                const int  hsrc = r8 | (g << 3);
                const bool own  = (slq == g);
#pragma unroll
                for (int s = 0; s < 16; ++s) {
                    const int t = g * 16 + s;
                    f32x4 w0 = *(const f32x4*)(lwb + t * LWS);
                    f32x4 w1 = *(const f32x4*)(lwb + t * LWS + 4);
                    f32x4 w2 = *(const f32x4*)(lwb + t * LWS + 8);
                    f32x4 w3 = *(const f32x4*)(lwb + t * LWS + 12);
                    float ps;
                    switch (s) {
                        case 0:  ps = p0[0]; break; case 1:  ps = p0[1]; break;
                        case 2:  ps = p1[0]; break; case 3:  ps = p1[1]; break;
                        case 4:  ps = p2[0]; break; case 5:  ps = p2[1]; break;
                        case 6:  ps = p3[0]; break; case 7:  ps = p3[1]; break;
                        case 8:  ps = p4[0]; break; case 9:  ps = p4[1]; break;
                        case 10: ps = p5[0]; break; case 11: ps = p5[1]; break;
                        case 12: ps = p6[0]; break; case 13: ps = p6[1]; break;
                        case 14: ps = p7[0]; break; default: ps = p7[1]; break;
                    }
                    float th_ = tanh_fast(ps);
                    float h = __shfl(th_, hsrc);
                    f32x2 hp; hp[0] = h; hp[1] = h;
                    f32x2 q;
                    q[0] = w0[0]; q[1] = w0[1]; pk_fma_bcast(p0, q, hp);
                    q[0] = w0[2]; q[1] = w0[3]; pk_fma_bcast(p1, q, hp);
                    q[0] = w1[0]; q[1] = w1[1]; pk_fma_bcast(p2, q, hp);
                    q[0] = w1[2]; q[1] = w1[3]; pk_fma_bcast(p3, q, hp);
                    q[0] = w2[0]; q[1] = w2[1]; pk_fma_bcast(p4, q, hp);
                    q[0] = w2[2]; q[1] = w2[3]; pk_fma_bcast(p5, q, hp);
                    q[0] = w3[0]; q[1] = w3[1]; pk_fma_bcast(p6, q, hp);
                    q[0] = w3[2]; q[1] = w3[3]; pk_fma_bcast(p7, q, hp);
                    if (own) {
                        switch (s) {
                            case 0:  p0[0] = h; break; case 1:  p0[1] = h; break;
                            case 2:  p1[0] = h; break; case 3:  p1[1] = h; break;
                            case 4:  p2[0] = h; break; case 5:  p2[1] = h; break;
                            case 6:  p3[0] = h; break; case 7:  p3[1] = h; break;
                            case 8:  p4[0] = h; break; case 9:  p4[1] = h; break;
                            case 10: p5[0] = h; break; case 11: p5[1] = h; break;
                            case 12: p6[0] = h; break; case 13: p6[1] = h; break;
                            case 14: p7[0] = h; break; default: p7[1] = h; break;
                        }
                    }
                }
            }
            float as[16] = {p0[0],p0[1],p1[0],p1[1],p2[0],p2[1],p3[0],p3[1],
                            p4[0],p4[1],p5[0],p5[1],p6[0],p6[1],p7[0],p7[1]};
            // h -> hbuf (LDS, for catch-up) and Hg (for later main-K)
            short8 h0, h1;
#pragma unroll
            for (int e = 0; e < 8; ++e) { h0[e] = f2bf(as[e]); h1[e] = f2bf(as[8 + e]); }
            *(short8*)&hbuf[srow * HBS + slq * 16]     = h0;
            *(short8*)&hbuf[srow * HBS + slq * 16 + 8] = h1;
            if (J < 9) {
                short* hg = Hg + (size_t)(bm + srow) * HG_COLS + j0 + slq * 16;
                *(short8*)hg = h0;
                *(short8*)(hg + 8) = h1;
            }
            if (J >= 8) {
                float* op = out + (size_t)(bm + srow) * OUT_DIM + (j0 - IN_DIM) + slq * 16;
#pragma unroll
                for (int qd = 0; qd < 4; ++qd) {
                    float4 o;
                    o.x = sigmoid_fast(as[qd * 4 + 0]);
                    o.y = sigmoid_fast(as[qd * 4 + 1]);
                    o.z = sigmoid_fast(as[qd * 4 + 2]);
                    o.w = sigmoid_fast(as[qd * 4 + 3]);
                    *(float4*)(op + qd * 4) = o;
                }
            }
        }
        __syncthreads();   // h_J in hbuf visible; seq's PreL reads done

        // =========== catch-up phase ===========
        if (gw) {
            if (J < 9) {
                const int j0p = j0 + 128;
                const int kb  = IN_DIM + j0;   // global k of h_J chunk
#pragma unroll
                for (int k32 = 0; k32 < 4; ++k32) {
                    int kl = k32 * 32;
                    short8 a0 = *(const short8*)&hbuf[(ar) * HBS + kl + kc8];
                    short8 a1 = *(const short8*)&hbuf[(16 + ar) * HBS + kl + kc8];
                    short8 b0 = ldB(j0p, 0, kb + kl);
                    short8 b1 = ldB(j0p, 1, kb + kl);
                    acc00 = __builtin_amdgcn_mfma_f32_16x16x32_bf16(a0, b0, acc00, 0, 0, 0);
                    acc01 = __builtin_amdgcn_mfma_f32_16x16x32_bf16(a0, b1, acc01, 0, 0, 0);
                    acc10 = __builtin_amdgcn_mfma_f32_16x16x32_bf16(a1, b0, acc10, 0, 0, 0);
                    acc11 = __builtin_amdgcn_mfma_f32_16x16x32_bf16(a1, b1, acc11, 0, 0, 0);
                }
                write_prel(j0p);
            }
        } else {
            if (J < 9) stage_lwf(j0 + 128);
        }
        __syncthreads();   // PreL(J+1), lwf(J+1) ready
    }
}

extern "C" void kernel_launch(void* const* d_in, const int* in_sizes, int n_in,
                              void* d_out, int out_size, void* d_ws, size_t ws_size,
                              hipStream_t stream)
{
    const float* x    = (const float*)d_in[0];
    const float* W    = (const float*)d_in[1];
    const float* bias = (const float*)d_in[2];
    float* out = (float*)d_out;
    short* Xbf = (short*)d_ws;
    short* Wbf = (short*)((char*)d_ws + WBF_OFF);
    short* Hg  = (short*)((char*)d_ws + HG_OFF);

    convert_x<<<dim3(B_ROWS * IN_DIM / 8 / 256), dim3(256), 0, stream>>>(x, Xbf);
    convert_w<<<dim3(M_DIM * P_DIM / 8 / 256), dim3(256), 0, stream>>>(W, Wbf);
    fused<<<dim3(B_ROWS / RB), dim3(512), 0, stream>>>(Xbf, Wbf, W, Hg, bias, out);
}

// Round 20
// 237.684 us; speedup vs baseline: 1.1688x; 1.1688x over previous
//
#include <hip/hip_runtime.h>
#include <hip/hip_bf16.h>
#include <math.h>

typedef short short8 __attribute__((ext_vector_type(8)));
typedef float f32x4  __attribute__((ext_vector_type(4)));
typedef float f32x2  __attribute__((ext_vector_type(2)));
typedef unsigned int u32;
typedef unsigned int u32x4 __attribute__((ext_vector_type(4)));

#define B_ROWS 8192
#define IN_DIM 1024
#define OUT_DIM 256
#define M_DIM 1280
#define P_DIM 2304
#define NJ 10
#define RB 32                  // rows per block -> 256 blocks, 1 block/CU, 8 waves
#define BK 128
#define HG_COLS 1152

// ws: Xbf bf16[8192][1024] ; Wbf bf16[1280][2304] ; Hg bf16[8192][1152]
#define WBF_OFF (B_ROWS * (size_t)IN_DIM * 2)
#define HG_OFF  (WBF_OFF + (size_t)M_DIM * P_DIM * 2)

__device__ __forceinline__ short f2bf(float x)
{
    __hip_bfloat16 h = __float2bfloat16(x);
    return *(short*)&h;
}

// tanh = 1 - 2/(e^{2x}+1); saturates correctly at +-inf.
__device__ __forceinline__ float tanh_fast(float x)
{
    float e = __expf(2.f * x);
    return 1.f - 2.f * __builtin_amdgcn_rcpf(e + 1.f);
}

__device__ __forceinline__ float sigmoid_fast(float y)
{
    return __builtin_amdgcn_rcpf(1.f + __expf(-y));
}

// packed dual-f32 FMA: d += w * h (h broadcast from lo)
__device__ __forceinline__ void pk_fma_bcast(f32x2& d, f32x2 w, f32x2 h)
{
    asm("v_pk_fma_f32 %0, %1, %2, %0 op_sel_hi:[1,0,1]"
        : "+v"(d) : "v"(w), "v"(h));
}

// barrier with LDS drain only -- in-flight GLOBAL loads stay in flight.
__device__ __forceinline__ void bar_lgkm()
{
    asm volatile("s_waitcnt lgkmcnt(0)" ::: "memory");
    __builtin_amdgcn_s_barrier();
}

__global__ __launch_bounds__(256)
void convert_x(const float* __restrict__ x, short* __restrict__ Xbf)
{
    int idx = blockIdx.x * 256 + threadIdx.x;
    int r  = idx >> 7;
    int c8 = (idx & 127) << 3;
    const float* src = x + (size_t)r * IN_DIM + c8;
    float4 a0 = *(const float4*)src;
    float4 a1 = *(const float4*)(src + 4);
    short8 s;
    s[0] = f2bf(a0.x); s[1] = f2bf(a0.y); s[2] = f2bf(a0.z); s[3] = f2bf(a0.w);
    s[4] = f2bf(a1.x); s[5] = f2bf(a1.y); s[6] = f2bf(a1.z); s[7] = f2bf(a1.w);
    *(short8*)(Xbf + (size_t)r * IN_DIM + c8) = s;
}

__global__ __launch_bounds__(256)
void convert_w(const float* __restrict__ W, short* __restrict__ Wbf)
{
    size_t e8 = ((size_t)blockIdx.x * 256 + threadIdx.x) * 8;
    float4 a0 = *(const float4*)(W + e8);
    float4 a1 = *(const float4*)(W + e8 + 4);
    short8 s;
    s[0] = f2bf(a0.x); s[1] = f2bf(a0.y); s[2] = f2bf(a0.z); s[3] = f2bf(a0.w);
    s[4] = f2bf(a1.x); s[5] = f2bf(a1.y); s[6] = f2bf(a1.z); s[7] = f2bf(a1.w);
    *(short8*)(Wbf + e8) = s;
}

// LDS union (81,920 B):
//  GEMM: xbuf[2] @0/@8192 (32x256B rows, XOR-swz) ; wbuf[2] @16384/@49152 (128x256B)
//  seq : PreL f32[32][132] @0 (16,896) ; lwf bf16[128][136] @16896 (34,816 -> 51,712)
#define XB0 0
#define XB1 8192
#define WB0 16384
#define WB1 49152
#define LWF_OFF 16896
#define PLS 132
#define LWS 136   // shorts per lwf row

__global__ __launch_bounds__(512, 1)
void fused(const short* __restrict__ Xbf, const short* __restrict__ Wbf,
           short* __restrict__ Hg, const float* __restrict__ bias,
           float* __restrict__ out)
{
    __shared__ __align__(16) char L[81920];

    const int tid  = threadIdx.x;
    const int lane = tid & 63;
    const int w    = tid >> 6;      // wave 0..7
    const int fr   = lane & 15;     // fragment row/col
    const int fq   = lane >> 4;     // k-quarter / row-quad
    const int rh   = w & 1;         // GEMM row-half (16 rows)
    const int wc   = w >> 1;        // GEMM col-pair (32 cols)
    const int r4   = lane & 3;      // seq: row within wave's 4
    const int sl   = lane >> 2;     // seq: slice 0..15 (8 u's)
    const int srow = w * 4 + r4;    // seq row 0..31
    const int bm   = blockIdx.x * RB;
    const int sa_r = tid >> 4;          // A staging row 0..31
    const int sa_c = (tid & 15) << 3;   // A staging col (shorts)
    const int n0 = wc * 32 + fr;
    const int n1 = n0 + 16;

#pragma unroll 1
    for (int J = 0; J < NJ; ++J) {
        const int j0 = J * 128;
        const int nt = (IN_DIM + j0) / BK;   // 8 + J

        f32x4 acc0 = {0.f, 0.f, 0.f, 0.f};
        f32x4 acc1 = {0.f, 0.f, 0.f, 0.f};

        __syncthreads();   // prev J fully done

        auto issue = [&](short8& ra, short8 (&rw)[4], int k0) {
            const short* s = (k0 < IN_DIM)
                ? (Xbf + (size_t)(bm + sa_r) * IN_DIM + k0 + sa_c)
                : (Hg + (size_t)(bm + sa_r) * HG_COLS + (k0 - IN_DIM) + sa_c);
            ra = *(const short8*)s;
#pragma unroll
            for (int c = 0; c < 4; ++c) {
                int idx = tid + c * 512;
                int n = idx >> 4, kc = (idx & 15) << 3;
                rw[c] = *(const short8*)(Wbf + (size_t)(j0 + n) * P_DIM + k0 + kc);
            }
        };
        auto lwrite = [&](short8& ra, short8 (&rw)[4], char* xw, char* ww) {
            *(short8*)(xw + ((sa_r * 256 + sa_c * 2) ^ ((sa_r & 15) << 4))) = ra;
#pragma unroll
            for (int c = 0; c < 4; ++c) {
                int idx = tid + c * 512;
                int n = idx >> 4, kc = (idx & 15) << 3;
                *(short8*)(ww + ((n * 256 + kc * 2) ^ ((n & 15) << 4))) = rw[c];
            }
        };
        auto domfma = [&](const char* xb, const char* wb) {
#pragma unroll
            for (int k32 = 0; k32 < 4; ++k32) {
                int kb = k32 * 64 + fq * 16;
                short8 a  = *(const short8*)(xb + (((rh * 16 + fr) * 256 + (kb ^ (fr << 4)))));
                short8 b0 = *(const short8*)(wb + ((n0 * 256 + (kb ^ (fr << 4)))));
                short8 b1 = *(const short8*)(wb + ((n1 * 256 + (kb ^ (fr << 4)))));
                acc0 = __builtin_amdgcn_mfma_f32_16x16x32_bf16(a, b0, acc0, 0, 0, 0);
                acc1 = __builtin_amdgcn_mfma_f32_16x16x32_bf16(a, b1, acc1, 0, 0, 0);
            }
        };

        // ---- GEMM: depth-2 register pipeline, counted-vmcnt barriers ------
        short8 ra0, ra1; short8 rw0[4], rw1[4];
        issue(ra0, rw0, 0);
        issue(ra1, rw1, BK);
        lwrite(ra0, rw0, L + XB0, L + WB0);

#pragma unroll 1
        for (int t = 0; t + 1 < nt; t += 2) {
            bar_lgkm();
            if (t + 2 < nt) issue(ra0, rw0, (t + 2) * BK);
            domfma(L + XB0, L + WB0);
            lwrite(ra1, rw1, L + XB1, L + WB1);
            bar_lgkm();
            if (t + 3 < nt) issue(ra1, rw1, (t + 3) * BK);
            domfma(L + XB1, L + WB1);
            if (t + 2 < nt) lwrite(ra0, rw0, L + XB0, L + WB0);
        }
        if (nt & 1) {          // peeled last tile (sits in buf0)
            bar_lgkm();
            domfma(L + XB0, L + WB0);
        }
        bar_lgkm();            // drain; LDS free for seq overlay

        // ---- epilogue: PreL = acc + bias; stage lwf bf16 (tri-zeroed) -----
        {
            float* PreL = (float*)L;
            float bv0 = bias[j0 + n0];
            float bv1 = bias[j0 + n1];
#pragma unroll
            for (int r = 0; r < 4; ++r) {
                int row = rh * 16 + fq * 4 + r;
                PreL[row * PLS + n0] = acc0[r] + bv0;
                PreL[row * PLS + n1] = acc1[r] + bv1;
            }
            short* lw = (short*)(L + LWF_OFF);
            int u = tid & 127, th = tid >> 7;     // th 0..3, covers 32 t's
            const short* wr_ = Wbf + (size_t)(j0 + u) * P_DIM + IN_DIM + j0 + th * 32;
#pragma unroll
            for (int s8 = 0; s8 < 4; ++s8) {
                short8 v = *(const short8*)(wr_ + s8 * 8);
#pragma unroll
                for (int e = 0; e < 8; ++e) {
                    int tt = th * 32 + s8 * 8 + e;
                    lw[tt * LWS + u] = (u > tt) ? v[e] : (short)0;
                }
            }
        }
        __syncthreads();

        // ---- read PreL into seq register pairs (8 u's per lane) ----
        f32x2 a01, a23, a45, a67;
        {
            const float* pr = (const float*)L + srow * PLS + sl * 8;
            a01 = *(const f32x2*)pr;
            a23 = *(const f32x2*)(pr + 2);
            a45 = *(const f32x2*)(pr + 4);
            a67 = *(const f32x2*)(pr + 6);
        }

        // ---- 128 seq steps: 1 ds_read_b128(bf16) + shfl + 4 pk_fma --------
        const short* lwb = (const short*)(L + LWF_OFF) + sl * 8;
#pragma unroll 1
        for (int g = 0; g < 16; ++g) {
            const int  hsrc = r4 | (g << 2);
            const bool own  = (sl == g);
#pragma unroll
            for (int s = 0; s < 8; ++s) {
                const int t = g * 8 + s;
                u32x4 wv = *(const u32x4*)(lwb + t * LWS);   // 8 bf16
                float ps;
                switch (s) {
                    case 0: ps = a01[0]; break; case 1: ps = a01[1]; break;
                    case 2: ps = a23[0]; break; case 3: ps = a23[1]; break;
                    case 4: ps = a45[0]; break; case 5: ps = a45[1]; break;
                    case 6: ps = a67[0]; break; default: ps = a67[1]; break;
                }
                float th_ = tanh_fast(ps);
                float h = __shfl(th_, hsrc);
                f32x2 hp; hp[0] = h; hp[1] = h;
                f32x2 q;
                q[0] = __uint_as_float(wv[0] << 16);
                q[1] = __uint_as_float(wv[0] & 0xffff0000u);
                pk_fma_bcast(a01, q, hp);
                q[0] = __uint_as_float(wv[1] << 16);
                q[1] = __uint_as_float(wv[1] & 0xffff0000u);
                pk_fma_bcast(a23, q, hp);
                q[0] = __uint_as_float(wv[2] << 16);
                q[1] = __uint_as_float(wv[2] & 0xffff0000u);
                pk_fma_bcast(a45, q, hp);
                q[0] = __uint_as_float(wv[3] << 16);
                q[1] = __uint_as_float(wv[3] & 0xffff0000u);
                pk_fma_bcast(a67, q, hp);
                if (own) {
                    switch (s) {
                        case 0: a01[0] = h; break; case 1: a01[1] = h; break;
                        case 2: a23[0] = h; break; case 3: a23[1] = h; break;
                        case 4: a45[0] = h; break; case 5: a45[1] = h; break;
                        case 6: a67[0] = h; break; default: a67[1] = h; break;
                    }
                }
            }
        }

        float as[8] = {a01[0], a01[1], a23[0], a23[1],
                       a45[0], a45[1], a67[0], a67[1]};

        // ---- write h to global H panel / output ----
        if (J < 9) {
            short8 hv;
#pragma unroll
            for (int e = 0; e < 8; ++e) hv[e] = f2bf(as[e]);
            *(short8*)(Hg + (size_t)(bm + srow) * HG_COLS + j0 + sl * 8) = hv;
        }
        if (J >= 8) {
            float* op = out + (size_t)(bm + srow) * OUT_DIM + (j0 - IN_DIM) + sl * 8;
            float4 o0, o1;
            o0.x = sigmoid_fast(as[0]); o0.y = sigmoid_fast(as[1]);
            o0.z = sigmoid_fast(as[2]); o0.w = sigmoid_fast(as[3]);
            o1.x = sigmoid_fast(as[4]); o1.y = sigmoid_fast(as[5]);
            o1.z = sigmoid_fast(as[6]); o1.w = sigmoid_fast(as[7]);
            *(float4*)op = o0;
            *(float4*)(op + 4) = o1;
        }
    }
}

extern "C" void kernel_launch(void* const* d_in, const int* in_sizes, int n_in,
                              void* d_out, int out_size, void* d_ws, size_t ws_size,
                              hipStream_t stream)
{
    const float* x    = (const float*)d_in[0];
    const float* W    = (const float*)d_in[1];
    const float* bias = (const float*)d_in[2];
    float* out = (float*)d_out;
    short* Xbf = (short*)d_ws;
    short* Wbf = (short*)((char*)d_ws + WBF_OFF);
    short* Hg  = (short*)((char*)d_ws + HG_OFF);

    convert_x<<<dim3(B_ROWS * IN_DIM / 8 / 256), dim3(256), 0, stream>>>(x, Xbf);
    convert_w<<<dim3(M_DIM * P_DIM / 8 / 256), dim3(256), 0, stream>>>(W, Wbf);
    fused<<<dim3(B_ROWS / RB), dim3(512), 0, stream>>>(Xbf, Wbf, Hg, bias, out);
}

// Round 21
// 226.602 us; speedup vs baseline: 1.2259x; 1.0489x over previous
//
#include <hip/hip_runtime.h>
#include <hip/hip_bf16.h>
#include <math.h>

typedef short short8 __attribute__((ext_vector_type(8)));
typedef float f32x16 __attribute__((ext_vector_type(16)));
typedef float f32x2  __attribute__((ext_vector_type(2)));
typedef unsigned int u32;
typedef unsigned int u32x4 __attribute__((ext_vector_type(4)));

#define B_ROWS 8192
#define IN_DIM 1024
#define OUT_DIM 256
#define M_DIM 1280
#define P_DIM 2304
#define NJ 10
#define RB 32                  // rows per block -> 256 blocks, 1 block/CU, 8 waves
#define BK 128
#define HG_COLS 1152

// ws: Xbf bf16[8192][1024] ; Wbf bf16[1280][2304] ; Hg bf16[8192][1152]
#define WBF_OFF (B_ROWS * (size_t)IN_DIM * 2)
#define HG_OFF  (WBF_OFF + (size_t)M_DIM * P_DIM * 2)

__device__ __forceinline__ short f2bf(float x)
{
    __hip_bfloat16 h = __float2bfloat16(x);
    return *(short*)&h;
}

// tanh = 1 - 2/(e^{2x}+1); saturates correctly at +-inf.
__device__ __forceinline__ float tanh_fast(float x)
{
    float e = __expf(2.f * x);
    return 1.f - 2.f * __builtin_amdgcn_rcpf(e + 1.f);
}

__device__ __forceinline__ float sigmoid_fast(float y)
{
    return __builtin_amdgcn_rcpf(1.f + __expf(-y));
}

__device__ __forceinline__ void pk_fma_bcast(f32x2& d, f32x2 w, f32x2 h)
{
    asm("v_pk_fma_f32 %0, %1, %2, %0 op_sel_hi:[1,0,1]"
        : "+v"(d) : "v"(w), "v"(h));
}

// async global->LDS DMA, 16 B per lane; LDS dest = uniform base + lane*16,
// global src is per-lane (carries the inverse swizzle).
__device__ __forceinline__ void gld16(const void* g, void* l)
{
    __builtin_amdgcn_global_load_lds(
        (const __attribute__((address_space(1))) void*)g,
        (__attribute__((address_space(3))) void*)l, 16, 0, 0);
}

__global__ __launch_bounds__(256)
void convert_x(const float* __restrict__ x, short* __restrict__ Xbf)
{
    int idx = blockIdx.x * 256 + threadIdx.x;
    int r  = idx >> 7;
    int c8 = (idx & 127) << 3;
    const float* src = x + (size_t)r * IN_DIM + c8;
    float4 a0 = *(const float4*)src;
    float4 a1 = *(const float4*)(src + 4);
    short8 s;
    s[0] = f2bf(a0.x); s[1] = f2bf(a0.y); s[2] = f2bf(a0.z); s[3] = f2bf(a0.w);
    s[4] = f2bf(a1.x); s[5] = f2bf(a1.y); s[6] = f2bf(a1.z); s[7] = f2bf(a1.w);
    *(short8*)(Xbf + (size_t)r * IN_DIM + c8) = s;
}

__global__ __launch_bounds__(256)
void convert_w(const float* __restrict__ W, short* __restrict__ Wbf)
{
    size_t e8 = ((size_t)blockIdx.x * 256 + threadIdx.x) * 8;
    float4 a0 = *(const float4*)(W + e8);
    float4 a1 = *(const float4*)(W + e8 + 4);
    short8 s;
    s[0] = f2bf(a0.x); s[1] = f2bf(a0.y); s[2] = f2bf(a0.z); s[3] = f2bf(a0.w);
    s[4] = f2bf(a1.x); s[5] = f2bf(a1.y); s[6] = f2bf(a1.z); s[7] = f2bf(a1.w);
    *(short8*)(Wbf + e8) = s;
}

// LDS (81,920 B):
//  GEMM: buf0 {A @0 (8K), W @8192 (32K)} ; buf1 {A @40960, W @49152}
//  seq overlay: PreL f32[32][132] @0 (16,896) ; lwf bf16[128][136] @16896 (-> 51,712)
#define XA0 0
#define XW0 8192
#define XA1 40960
#define XW1 49152
#define LWF_OFF 16896
#define PLS 132
#define LWS 136   // shorts per lwf row

__global__ __launch_bounds__(512, 1)
void fused(const short* __restrict__ Xbf, const short* __restrict__ Wbf,
           short* __restrict__ Hg, const float* __restrict__ bias,
           float* __restrict__ out)
{
    __shared__ __align__(16) char L[81920];

    const int tid  = threadIdx.x;
    const int lane = tid & 63;
    const int w    = tid >> 6;      // wave 0..7
    const int rl   = lane & 31;     // fragment row/col (32x32)
    const int lh   = lane >> 5;     // k-half within 16-chunk
    const int cg   = w >> 1;        // col group 0..3 (32 cols)
    const int kh   = w & 1;         // K-half 0/1
    const int r4   = lane & 3;      // seq: row within wave's 4
    const int sl   = lane >> 2;     // seq: slice 0..15 (8 u's)
    const int srow = w * 4 + r4;    // seq row 0..31
    const int bm   = blockIdx.x * RB;
    const int ccol = cg * 32 + rl;  // GEMM output col 0..127
    const int swz  = (rl & 15) << 4;

#pragma unroll 1
    for (int J = 0; J < NJ; ++J) {
        const int j0 = J * 128;
        const int nt = (IN_DIM + j0) / BK;   // 8 + J

        f32x16 acc;
#pragma unroll
        for (int r = 0; r < 16; ++r) acc[r] = 0.f;

        __syncthreads();   // prev J fully done (drains seq's global h-stores)

        // 5 DMA issues per wave per tile: 1 A-chunk (4 rows) + 4 W-chunks
        auto issue = [&](int k0, char* xb, char* wb) {
            {
                int R  = 4 * w + (lane >> 4);
                int sb = ((lane & 15) << 4) ^ ((R & 15) << 4);
                const short* g = (k0 < IN_DIM)
                    ? (Xbf + (size_t)(bm + R) * IN_DIM + k0)
                    : (Hg + (size_t)(bm + R) * HG_COLS + (k0 - IN_DIM));
                gld16((const char*)g + sb, xb + w * 1024);
            }
#pragma unroll
            for (int c = 0; c < 4; ++c) {
                int j  = 4 * w + c;              // W LDS row-quad 0..31
                int R  = 4 * j + (lane >> 4);    // W tile row 0..127
                int sb = ((lane & 15) << 4) ^ ((R & 15) << 4);
                const short* g = Wbf + (size_t)(j0 + R) * P_DIM + k0;
                gld16((const char*)g + sb, wb + j * 1024);
            }
        };
        auto domfma = [&](const char* xb, const char* wb) {
#pragma unroll
            for (int c = 0; c < 4; ++c) {
                int kb = kh * 128 + c * 32 + lh * 16;
                short8 a = *(const short8*)(xb + rl * 256 + (kb ^ swz));
                short8 b = *(const short8*)(wb + ccol * 256 + (kb ^ swz));
                acc = __builtin_amdgcn_mfma_f32_32x32x16_bf16(a, b, acc, 0, 0, 0);
            }
        };

        // ---- GEMM: DMA depth-2 pipeline, counted vmcnt ----
        issue(0, L + XA0, L + XW0);
        issue(BK, L + XA1, L + XW1);
#pragma unroll 1
        for (int t = 0; t < nt; ++t) {
            if (t + 1 < nt) asm volatile("s_waitcnt vmcnt(5)" ::: "memory");
            else            asm volatile("s_waitcnt vmcnt(0)" ::: "memory");
            __builtin_amdgcn_s_barrier();      // tile t fully in LDS
            const char* xb = (t & 1) ? L + XA1 : L + XA0;
            const char* wb = (t & 1) ? L + XW1 : L + XW0;
            domfma(xb, wb);
            asm volatile("s_waitcnt lgkmcnt(0)" ::: "memory");
            __builtin_amdgcn_s_barrier();      // all reads of buf[t&1] done
            if (t + 2 < nt)
                issue((t + 2) * BK, (t & 1) ? L + XA1 : L + XA0,
                                    (t & 1) ? L + XW1 : L + XW0);
        }

        // ---- epilogue: combine K-halves into PreL (C layout: col=lane&31,
        //      row=(r&3)+8*(r>>2)+4*lh), then stage lwf ----
        float* PreL = (float*)L;
        if (kh == 0) {
            float bv = bias[j0 + ccol];
#pragma unroll
            for (int r = 0; r < 16; ++r) {
                int rg = (r & 3) + 8 * (r >> 2) + 4 * lh;
                PreL[rg * PLS + ccol] = acc[r] + bv;
            }
        }
        __syncthreads();
        if (kh == 1) {
#pragma unroll
            for (int r = 0; r < 16; ++r) {
                int rg = (r & 3) + 8 * (r >> 2) + 4 * lh;
                PreL[rg * PLS + ccol] += acc[r];
            }
        }
        {
            short* lw = (short*)(L + LWF_OFF);
            int u = tid & 127, th = tid >> 7;     // th 0..3, 32 t's each
            const short* wr_ = Wbf + (size_t)(j0 + u) * P_DIM + IN_DIM + j0 + th * 32;
#pragma unroll
            for (int s8 = 0; s8 < 4; ++s8) {
                short8 v = *(const short8*)(wr_ + s8 * 8);
#pragma unroll
                for (int e = 0; e < 8; ++e) {
                    int tt = th * 32 + s8 * 8 + e;
                    lw[tt * LWS + u] = (u > tt) ? v[e] : (short)0;
                }
            }
        }
        __syncthreads();

        // ---- read PreL into seq register pairs (8 u's per lane) ----
        f32x2 a01, a23, a45, a67;
        {
            const float* pr = (const float*)L + srow * PLS + sl * 8;
            a01 = *(const f32x2*)pr;
            a23 = *(const f32x2*)(pr + 2);
            a45 = *(const f32x2*)(pr + 4);
            a67 = *(const f32x2*)(pr + 6);
        }

        // ---- 128 seq steps: 1 ds_read_b128(bf16) + shfl + 4 pk_fma --------
        const short* lwb = (const short*)(L + LWF_OFF) + sl * 8;
#pragma unroll 1
        for (int g = 0; g < 16; ++g) {
            const int  hsrc = r4 | (g << 2);
            const bool own  = (sl == g);
#pragma unroll
            for (int s = 0; s < 8; ++s) {
                const int t = g * 8 + s;
                u32x4 wv = *(const u32x4*)(lwb + t * LWS);   // 8 bf16
                float ps;
                switch (s) {
                    case 0: ps = a01[0]; break; case 1: ps = a01[1]; break;
                    case 2: ps = a23[0]; break; case 3: ps = a23[1]; break;
                    case 4: ps = a45[0]; break; case 5: ps = a45[1]; break;
                    case 6: ps = a67[0]; break; default: ps = a67[1]; break;
                }
                float th_ = tanh_fast(ps);
                float h = __shfl(th_, hsrc);
                f32x2 hp; hp[0] = h; hp[1] = h;
                f32x2 q;
                q[0] = __uint_as_float(wv[0] << 16);
                q[1] = __uint_as_float(wv[0] & 0xffff0000u);
                pk_fma_bcast(a01, q, hp);
                q[0] = __uint_as_float(wv[1] << 16);
                q[1] = __uint_as_float(wv[1] & 0xffff0000u);
                pk_fma_bcast(a23, q, hp);
                q[0] = __uint_as_float(wv[2] << 16);
                q[1] = __uint_as_float(wv[2] & 0xffff0000u);
                pk_fma_bcast(a45, q, hp);
                q[0] = __uint_as_float(wv[3] << 16);
                q[1] = __uint_as_float(wv[3] & 0xffff0000u);
                pk_fma_bcast(a67, q, hp);
                if (own) {
                    switch (s) {
                        case 0: a01[0] = h; break; case 1: a01[1] = h; break;
                        case 2: a23[0] = h; break; case 3: a23[1] = h; break;
                        case 4: a45[0] = h; break; case 5: a45[1] = h; break;
                        case 6: a67[0] = h; break; default: a67[1] = h; break;
                    }
                }
            }
        }

        float as[8] = {a01[0], a01[1], a23[0], a23[1],
                       a45[0], a45[1], a67[0], a67[1]};

        // ---- write h to global H panel / output ----
        if (J < 9) {
            short8 hv;
#pragma unroll
            for (int e = 0; e < 8; ++e) hv[e] = f2bf(as[e]);
            *(short8*)(Hg + (size_t)(bm + srow) * HG_COLS + j0 + sl * 8) = hv;
        }
        if (J >= 8) {
            float* op = out + (size_t)(bm + srow) * OUT_DIM + (j0 - IN_DIM) + sl * 8;
            float4 o0, o1;
            o0.x = sigmoid_fast(as[0]); o0.y = sigmoid_fast(as[1]);
            o0.z = sigmoid_fast(as[2]); o0.w = sigmoid_fast(as[3]);
            o1.x = sigmoid_fast(as[4]); o1.y = sigmoid_fast(as[5]);
            o1.z = sigmoid_fast(as[6]); o1.w = sigmoid_fast(as[7]);
            *(float4*)op = o0;
            *(float4*)(op + 4) = o1;
        }
    }
}

extern "C" void kernel_launch(void* const* d_in, const int* in_sizes, int n_in,
                              void* d_out, int out_size, void* d_ws, size_t ws_size,
                              hipStream_t stream)
{
    const float* x    = (const float*)d_in[0];
    const float* W    = (const float*)d_in[1];
    const float* bias = (const float*)d_in[2];
    float* out = (float*)d_out;
    short* Xbf = (short*)d_ws;
    short* Wbf = (short*)((char*)d_ws + WBF_OFF);
    short* Hg  = (short*)((char*)d_ws + HG_OFF);

    convert_x<<<dim3(B_ROWS * IN_DIM / 8 / 256), dim3(256), 0, stream>>>(x, Xbf);
    convert_w<<<dim3(M_DIM * P_DIM / 8 / 256), dim3(256), 0, stream>>>(W, Wbf);
    fused<<<dim3(B_ROWS / RB), dim3(512), 0, stream>>>(Xbf, Wbf, Hg, bias, out);
}